// Round 9
// baseline (207.097 us; speedup 1.0000x reference)
//
#include <hip/hip_runtime.h>
#include <hip/hip_bf16.h>

// SAGEConv: out = x @ W_self^T + b_self + segsum(x[col]*w, row) @ W_neigh^T + b_neigh
// N=100000, E=1600000, C=64. fp32 tensors; edge_index int32 [2*E] (dst|src); out fp32.
//
// R10: fine LDS sort + register accumulation (zero fp32 atomics), agg 696->64us.
// R11: bin rebuilt (1024 thr, stageb[] kills binary search, shfl scan): 43->~25us.
// R13: agg eighth-wave gather, reduce-scatter, bf16 end-to-end: 215->195us. <-- best
// R14/R15: proj-into-agg fusion attempts REGRESSED (epilogue latency on the
//      critical path / VGPR 72 halved occupancy on the latency-bound gather).
// R16: R13 revert + conv-in-bin + 3-barrier scan: 199.9 (+5 vs R13; conv tail
//      at bin's ~1 block/CU residency is serial, not hidden).
// R17: conversions back in prep (R13-proven). agg gather: rows processed in
//      PAIRS (rA=wv+16m, rB=rA+8) with a merged loop issuing 4 independent
//      gathers before FMAs -> 2x memory-level parallelism on the ~600cy L3
//      gather path (agg was ~70% memory-stalled, VALU 28%). Interleaved A/B
//      reduce-scatter. __launch_bounds__(512,8) pins VGPR<=64 (8 waves/SIMD).
// R18: R17 with FMA_ROW macro fixed (param `w` collided with .w member).
// R19: identical resubmit of R18 (round-8 bench was a container-level infra
//      failure, same signature as round 1; audit found no fault/hang path).

#define C 64
#define BKT 128                 // nodes per bucket
#define MAXB 800                // max bucket count supported by static LDS
#define BINT 6144               // edges per bin block
#define BTHR 1024               // bin threads per block (16 waves)
#define CAP 2560                // agg: edges sorted per chunk (bucket avg 2046)

typedef __attribute__((ext_vector_type(8))) short bf16x8;
typedef __attribute__((ext_vector_type(4))) float f32x4;

__device__ inline unsigned short f2bf(float f) {
    union { __hip_bfloat16 h; unsigned short u; } c;
    c.h = __float2bfloat16(f);
    return c.u;
}

__device__ inline float bflo16(unsigned int u) {
    return __int_as_float((int)(u << 16));
}
__device__ inline float bfhi16(unsigned int u) {
    return __int_as_float((int)(u & 0xFFFF0000u));
}

#define FMA_ROW(A, U, W) \
    A##0 += (W) * bflo16((U).x); A##1 += (W) * bfhi16((U).x); \
    A##2 += (W) * bflo16((U).y); A##3 += (W) * bfhi16((U).y); \
    A##4 += (W) * bflo16((U).z); A##5 += (W) * bfhi16((U).z); \
    A##6 += (W) * bflo16((U).w); A##7 += (W) * bfhi16((U).w)

// --------------------------------------------------------------------------
// prep: bucket histogram (LDS pre-agg) + x -> bf16 + weights -> bf16.
// (R13-proven placement: conversion here beats bin-tail, R16 post-mortem.)
// --------------------------------------------------------------------------
__global__ __launch_bounds__(256) void prep_kernel(
        const int* __restrict__ ei, int* __restrict__ bhist, int E, int NBK,
        const float* __restrict__ x, unsigned short* __restrict__ xb, int n4,
        const float* __restrict__ Ws, const float* __restrict__ Wn,
        unsigned short* __restrict__ Wsb, unsigned short* __restrict__ Wnb) {
    __shared__ int lh[MAXB];
    const int t = threadIdx.x;
    for (int i = t; i < NBK; i += 256) lh[i] = 0;
    __syncthreads();
    const int gtid = blockIdx.x * 256 + t;
    const int gs = gridDim.x * 256;
    for (int e = gtid; e < E; e += gs)
        atomicAdd(&lh[ei[e] >> 7], 1);
    __syncthreads();
    for (int i = t; i < NBK; i += 256)
        if (lh[i]) atomicAdd(&bhist[i], lh[i]);
    const float4* x4 = (const float4*)x;
    ushort4* xb4 = (ushort4*)xb;
    for (int i = gtid; i < n4; i += gs) {
        float4 v = x4[i];
        ushort4 o;
        o.x = f2bf(v.x); o.y = f2bf(v.y); o.z = f2bf(v.z); o.w = f2bf(v.w);
        xb4[i] = o;
    }
    if (gtid < 1024) {   // 64*64 floats = 1024 float4 per weight matrix
        float4 v = ((const float4*)Ws)[gtid];
        ushort4 o;
        o.x = f2bf(v.x); o.y = f2bf(v.y); o.z = f2bf(v.z); o.w = f2bf(v.w);
        ((ushort4*)Wsb)[gtid] = o;
        v = ((const float4*)Wn)[gtid];
        o.x = f2bf(v.x); o.y = f2bf(v.y); o.z = f2bf(v.z); o.w = f2bf(v.w);
        ((ushort4*)Wnb)[gtid] = o;
    }
}

// --------------------------------------------------------------------------
// scan: exclusive scan of bhist[NBK] -> boffs[NBK+1], copy to bcur. 1 block.
// --------------------------------------------------------------------------
__global__ __launch_bounds__(1024) void scan_kernel(
        const int* __restrict__ bhist, int* __restrict__ boffs,
        int* __restrict__ bcur, int NBK) {
    __shared__ int s[1024];
    const int t = threadIdx.x;
    s[t] = (t < NBK) ? bhist[t] : 0;
    __syncthreads();
    for (int off = 1; off < 1024; off <<= 1) {
        int v = 0;
        if (t >= off) v = s[t - off];
        __syncthreads();
        if (t >= off) s[t] += v;
        __syncthreads();
    }
    if (t < NBK) {
        int e = (t > 0) ? s[t - 1] : 0;
        boffs[t] = e;
        bcur[t] = e;
        if (t == NBK - 1) boffs[NBK] = s[t];
    }
}

// --------------------------------------------------------------------------
// bin: coarse counting sort by 128-node bucket, LDS-staged coalesced writes.
// 1024 threads (16 waves); shfl_up wave scan; bucket id stored per staged
// edge -> direct final address (adj[b] + i), no binary search.
// --------------------------------------------------------------------------
__global__ __launch_bounds__(BTHR) void bin_kernel(
        const int* __restrict__ ei, const float* __restrict__ ew,
        int* __restrict__ bcur,
        int2* __restrict__ sorted, int E, int NBK) {
    __shared__ int2 stage[BINT];                 // 48 KB
    __shared__ unsigned short stageb[BINT];      // 12 KB
    __shared__ int h[MAXB];                      // histogram
    __shared__ int cur[MAXB];                    // running scatter cursor
    __shared__ int adj[MAXB];                    // globalBase - localStart
    __shared__ int wsum[16];

    const int t = threadIdx.x;
    const int lane = t & 63;
    const int wv = t >> 6;                       // 0..15
    const int e0 = blockIdx.x * BINT;
    const int cnt = min(BINT, E - e0);

    for (int i = t; i < NBK; i += BTHR) h[i] = 0;
    __syncthreads();

    // pass 1: histogram of bucket ids
#pragma unroll
    for (int k = 0; k < BINT / BTHR; ++k) {
        const int idx = t + k * BTHR;
        if (idx < cnt) atomicAdd(&h[ei[e0 + idx] >> 7], 1);
    }
    __syncthreads();

    // exclusive scan of h[0..NBK): wave shfl scan + 16-entry combine.
    const int val = (t < NBK) ? h[t] : 0;
    int v = val;
#pragma unroll
    for (int off = 1; off < 64; off <<= 1) {
        const int u = __shfl_up(v, off);
        if (lane >= off) v += u;
    }
    if (lane == 63) wsum[wv] = v;
    __syncthreads();
    if (t < 64) {
        int s = (lane < 16) ? wsum[lane] : 0;
#pragma unroll
        for (int off = 1; off < 16; off <<= 1) {
            const int u = __shfl_up(s, off);
            if (lane >= off) s += u;
        }
        if (lane < 16) wsum[lane] = s;           // inclusive wave-sum scan
    }
    __syncthreads();
    if (t < NBK) {
        const int incl = v + ((wv > 0) ? wsum[wv - 1] : 0);
        const int excl = incl - val;
        cur[t] = excl;
        const int g = val ? atomicAdd(&bcur[t], val) : 0;
        adj[t] = g - excl;
    }
    __syncthreads();

    // pass 2: LDS scatter into bucket-sorted order, recording bucket id
#pragma unroll
    for (int k = 0; k < BINT / BTHR; ++k) {
        const int idx = t + k * BTHR;
        if (idx < cnt) {
            const int e = e0 + idx;
            const int d = ei[e];
            const int s = ei[E + e];
            const float w = ew[e];
            const int b = d >> 7;
            const int dl = d & 127;
            const int p = atomicAdd(&cur[b], 1);
            stage[p] = make_int2((dl << 17) | s, __float_as_int(w));
            stageb[p] = (unsigned short)b;
        }
    }
    __syncthreads();

    // write-out: coalesced within each bucket run; no search needed
    for (int i = t; i < cnt; i += BTHR) {
        const int b = stageb[i];
        sorted[adj[b] + i] = stage[i];
    }
}

// --------------------------------------------------------------------------
// agg v10: one block (512 thr, 8 waves) per bucket. Fine counting sort in
// LDS (3-barrier shfl scan), then PAIRED-row gather: wave wv owns rows
// wv+8k; pairs (rA=wv+16m, rB=rA+8) run a merged loop issuing 4 independent
// uint4 gathers (2 per row) before any FMA -> 2x in-flight vs sequential
// rows. Per-row drains handle tails; interleaved A/B reduce-scatter (7+7
// shuffles, ILP); each lane owns 1 channel -> coalesced bf16 row write.
// fp32 agg used only as multi-chunk spill.
// --------------------------------------------------------------------------
__global__ __launch_bounds__(512, 8) void agg_kernel(
        const unsigned short* __restrict__ xb,   // bf16, row stride 64
        const int2* __restrict__ sorted,
        const int* __restrict__ boffs,
        float* __restrict__ agg,                 // fp32 spill (multi-chunk only)
        unsigned short* __restrict__ aggb,       // bf16 output
        int N) {
    __shared__ int2 meta2[CAP];             // 20 KB
    __shared__ int lcnt[BKT];
    __shared__ int lincl[BKT];
    __shared__ int lcur[BKT];

    const int t = threadIdx.x;
    const int b = blockIdx.x;
    const int node0 = b << 7;
    const int lane = t & 63;
    const int wv = t >> 6;                  // 0..7
    const int oct = lane >> 3;              // edge slot 0..7
    const int co = lane & 7;                // uint4 index within row

    const bool h1 = (lane & 8) != 0;
    const bool h2 = (lane & 16) != 0;
    const bool h3 = (lane & 32) != 0;
    // channel this lane owns after reduce-scatter
    const int ch = co * 8 + (h1 ? 4 : 0) + (h2 ? 2 : 0) + (h3 ? 1 : 0);

    const uint4* xb8 = (const uint4*)xb;    // row stride 8 uint4

    const int beg = boffs[b];
    const int end = boffs[b + 1];

    int chunk = beg;
    do {
        const int cc = (end - chunk < CAP) ? (end - chunk) : CAP;  // may be 0

        for (int i = t; i < BKT; i += 512) lcnt[i] = 0;
        __syncthreads();

        // pass 1: histogram of local dst (coalesced global reads)
        for (int i = t; i < cc; i += 512)
            atomicAdd(&lcnt[sorted[chunk + i].x >> 17], 1);
        __syncthreads();

        // 128-entry inclusive scan: 2-wave shfl scan + combine (3 barriers)
        if (t < BKT) {
            int acc = lcnt[t];
#pragma unroll
            for (int off = 1; off < 64; off <<= 1) {
                const int u = __shfl_up(acc, off);
                if (lane >= off) acc += u;
            }
            lincl[t] = acc;
        }
        __syncthreads();
        if (t >= 64 && t < BKT) lincl[t] += lincl[63];
        __syncthreads();
        if (t < BKT) lcur[t] = lincl[t] - lcnt[t];   // exclusive start
        __syncthreads();

        // pass 2: LDS scatter into fine-sorted order (src, w)
        for (int i = t; i < cc; i += 512) {
            const int2 m = sorted[chunk + i];
            const int dl = m.x >> 17;
            const int p = atomicAdd(&lcur[dl], 1);
            meta2[p] = make_int2(m.x & 0x1FFFF, m.y);
        }
        __syncthreads();

        const bool first = (chunk == beg);
        const bool last = (chunk + CAP >= end);

        // paired-row aggregate: 8 pairs per wave
        for (int m = 0; m < 8; ++m) {
            const int rA = wv + (m << 4);
            const int rB = rA + 8;
            const int sA1 = lincl[rA];
            const int sA0 = sA1 - lcnt[rA];
            const int sB1 = lincl[rB];
            const int sB0 = sB1 - lcnt[rB];

            float aA0=0.f,aA1=0.f,aA2=0.f,aA3=0.f,aA4=0.f,aA5=0.f,aA6=0.f,aA7=0.f;
            float aB0=0.f,aB1=0.f,aB2=0.f,aB3=0.f,aB4=0.f,aB5=0.f,aB6=0.f,aB7=0.f;

            int jA = sA0 + oct;
            int jB = sB0 + oct;

            // merged steady state: 4 independent gathers in flight
            while (jA + 8 < sA1 && jB + 8 < sB1) {
                const int2 mA0 = meta2[jA];
                const int2 mA1 = meta2[jA + 8];
                const int2 mB0 = meta2[jB];
                const int2 mB1 = meta2[jB + 8];
                const uint4 uA0 = xb8[(unsigned)mA0.x * 8u + co];
                const uint4 uA1 = xb8[(unsigned)mA1.x * 8u + co];
                const uint4 uB0 = xb8[(unsigned)mB0.x * 8u + co];
                const uint4 uB1 = xb8[(unsigned)mB1.x * 8u + co];
                const float wA0 = __int_as_float(mA0.y);
                const float wA1 = __int_as_float(mA1.y);
                const float wB0 = __int_as_float(mB0.y);
                const float wB1 = __int_as_float(mB1.y);
                FMA_ROW(aA, uA0, wA0); FMA_ROW(aA, uA1, wA1);
                FMA_ROW(aB, uB0, wB0); FMA_ROW(aB, uB1, wB1);
                jA += 16; jB += 16;
            }
            // drain A
            for (; jA + 8 < sA1; jA += 16) {
                const int2 m0 = meta2[jA];
                const int2 m1 = meta2[jA + 8];
                const uint4 u0 = xb8[(unsigned)m0.x * 8u + co];
                const uint4 u1 = xb8[(unsigned)m1.x * 8u + co];
                const float w0 = __int_as_float(m0.y);
                const float w1 = __int_as_float(m1.y);
                FMA_ROW(aA, u0, w0); FMA_ROW(aA, u1, w1);
            }
            if (jA < sA1) {
                const int2 m0 = meta2[jA];
                const uint4 u0 = xb8[(unsigned)m0.x * 8u + co];
                const float w0 = __int_as_float(m0.y);
                FMA_ROW(aA, u0, w0);
            }
            // drain B
            for (; jB + 8 < sB1; jB += 16) {
                const int2 m0 = meta2[jB];
                const int2 m1 = meta2[jB + 8];
                const uint4 u0 = xb8[(unsigned)m0.x * 8u + co];
                const uint4 u1 = xb8[(unsigned)m1.x * 8u + co];
                const float w0 = __int_as_float(m0.y);
                const float w1 = __int_as_float(m1.y);
                FMA_ROW(aB, u0, w0); FMA_ROW(aB, u1, w1);
            }
            if (jB < sB1) {
                const int2 m0 = meta2[jB];
                const uint4 u0 = xb8[(unsigned)m0.x * 8u + co];
                const float w0 = __int_as_float(m0.y);
                FMA_ROW(aB, u0, w0);
            }

            // interleaved A/B reduce-scatter (shuffle ILP)
            float rsA0 = __shfl_xor(h1 ? aA0 : aA4, 8);
            float rsA1 = __shfl_xor(h1 ? aA1 : aA5, 8);
            float rsA2 = __shfl_xor(h1 ? aA2 : aA6, 8);
            float rsA3 = __shfl_xor(h1 ? aA3 : aA7, 8);
            float rsB0 = __shfl_xor(h1 ? aB0 : aB4, 8);
            float rsB1 = __shfl_xor(h1 ? aB1 : aB5, 8);
            float rsB2 = __shfl_xor(h1 ? aB2 : aB6, 8);
            float rsB3 = __shfl_xor(h1 ? aB3 : aB7, 8);
            const float bA0 = (h1 ? aA4 : aA0) + rsA0;
            const float bA1 = (h1 ? aA5 : aA1) + rsA1;
            const float bA2 = (h1 ? aA6 : aA2) + rsA2;
            const float bA3 = (h1 ? aA7 : aA3) + rsA3;
            const float bB0 = (h1 ? aB4 : aB0) + rsB0;
            const float bB1 = (h1 ? aB5 : aB1) + rsB1;
            const float bB2 = (h1 ? aB6 : aB2) + rsB2;
            const float bB3 = (h1 ? aB7 : aB3) + rsB3;
            float r4A0 = __shfl_xor(h2 ? bA0 : bA2, 16);
            float r4A1 = __shfl_xor(h2 ? bA1 : bA3, 16);
            float r4B0 = __shfl_xor(h2 ? bB0 : bB2, 16);
            float r4B1 = __shfl_xor(h2 ? bB1 : bB3, 16);
            const float cA0 = (h2 ? bA2 : bA0) + r4A0;
            const float cA1 = (h2 ? bA3 : bA1) + r4A1;
            const float cB0 = (h2 ? bB2 : bB0) + r4B0;
            const float cB1 = (h2 ? bB3 : bB1) + r4B1;
            float r6A = __shfl_xor(h3 ? cA0 : cA1, 32);
            float r6B = __shfl_xor(h3 ? cB0 : cB1, 32);
            float vA = (h3 ? cA1 : cA0) + r6A;
            float vB = (h3 ? cB1 : cB0) + r6B;

            const int nodeA = node0 + rA;
            if (nodeA < N) {
                const size_t offA = (size_t)nodeA * C + ch;
                if (last) {
                    if (!first) vA += agg[offA];
                    aggb[offA] = f2bf(vA);
                } else {
                    if (first) agg[offA] = vA;
                    else       agg[offA] += vA;
                }
            }
            const int nodeB = node0 + rB;
            if (nodeB < N) {
                const size_t offB = (size_t)nodeB * C + ch;
                if (last) {
                    if (!first) vB += agg[offB];
                    aggb[offB] = f2bf(vB);
                } else {
                    if (first) agg[offB] = vB;
                    else       agg[offB] += vB;
                }
            }
        }
        chunk += CAP;
        __syncthreads();            // protect lcnt reuse next chunk
    } while (chunk < end);
}

// --------------------------------------------------------------------------
// fallback (ws too small / N too big): R2 atomic scatter + fp32 proj.
// --------------------------------------------------------------------------
__global__ __launch_bounds__(256) void scatter_kernel(
        const float* __restrict__ x, const int* __restrict__ ei,
        const float* __restrict__ ew, float* __restrict__ agg, int E) {
    const int lane = threadIdx.x & 63;
    const int wid = (blockIdx.x * blockDim.x + threadIdx.x) >> 6;
    const int nw = (gridDim.x * blockDim.x) >> 6;
    for (int base = wid * 64; base < E; base += nw * 64) {
        const int e = base + lane;
        int dst = 0, src = 0; float w = 0.f;
        if (e < E) { dst = ei[e]; src = ei[E + e]; w = ew[e]; }
        const int cnt = min(64, E - base);
        for (int j = 0; j < cnt; ++j) {
            const int d = __shfl(dst, j);
            const int s = __shfl(src, j);
            const float wj = __shfl(w, j);
            atomicAdd(&agg[d * C + lane], x[s * C + lane] * wj);
        }
    }
}

__device__ inline bf16x8 cvt8(const float* __restrict__ p) {
    f32x4 lo = *(const f32x4*)p;
    f32x4 hi = *(const f32x4*)(p + 4);
    union { bf16x8 v; __hip_bfloat16 e[8]; } u;
#pragma unroll
    for (int j = 0; j < 4; ++j) u.e[j] = __float2bfloat16(lo[j]);
#pragma unroll
    for (int j = 0; j < 4; ++j) u.e[4 + j] = __float2bfloat16(hi[j]);
    return u.v;
}

__global__ __launch_bounds__(256) void proj_kernel(
        const float* __restrict__ x, const float* __restrict__ agg,
        const float* __restrict__ Ws, const float* __restrict__ bs,
        const float* __restrict__ Wn, const float* __restrict__ bn,
        float* __restrict__ out, int N) {
    const int lane = threadIdx.x & 63;
    const int wid = (blockIdx.x * blockDim.x + threadIdx.x) >> 6;
    const int l15 = lane & 15;
    const int quad = lane >> 4;
    const int nTiles = N >> 4;
    if (wid >= nTiles) return;
    const int m0 = wid << 4;

    bf16x8 bsf[4][2], bnf[4][2];
#pragma unroll
    for (int tt = 0; tt < 4; ++tt) {
        const int o = tt * 16 + l15;
#pragma unroll
        for (int h = 0; h < 2; ++h) {
            bsf[tt][h] = cvt8(Ws + o * C + h * 32 + quad * 8);
            bnf[tt][h] = cvt8(Wn + o * C + h * 32 + quad * 8);
        }
    }

    const int m = m0 + l15;
    bf16x8 ax[2], ag[2];
#pragma unroll
    for (int h = 0; h < 2; ++h) {
        ax[h] = cvt8(x + m * C + h * 32 + quad * 8);
        ag[h] = cvt8(agg + m * C + h * 32 + quad * 8);
    }

#pragma unroll
    for (int tt = 0; tt < 4; ++tt) {
        f32x4 acc = {0.f, 0.f, 0.f, 0.f};
        acc = __builtin_amdgcn_mfma_f32_16x16x32_bf16(ax[0], bsf[tt][0], acc, 0, 0, 0);
        acc = __builtin_amdgcn_mfma_f32_16x16x32_bf16(ax[1], bsf[tt][1], acc, 0, 0, 0);
        acc = __builtin_amdgcn_mfma_f32_16x16x32_bf16(ag[0], bnf[tt][0], acc, 0, 0, 0);
        acc = __builtin_amdgcn_mfma_f32_16x16x32_bf16(ag[1], bnf[tt][1], acc, 0, 0, 0);
        const int o = tt * 16 + l15;
        const float bias = bs[o] + bn[o];
#pragma unroll
        for (int r = 0; r < 4; ++r)
            out[(m0 + quad * 4 + r) * C + o] = acc[r] + bias;
    }
}

// --------------------------------------------------------------------------
// projb: main-path proj. All operands already bf16 (xb, aggb, Wsb, Wnb) ->
// pure 16B loads + MFMA, no conversions. HBM: 12.8+12.8 read, 25.6 write.
// --------------------------------------------------------------------------
__global__ __launch_bounds__(256) void projb_kernel(
        const unsigned short* __restrict__ xb,
        const unsigned short* __restrict__ aggb,
        const unsigned short* __restrict__ Wsb, const float* __restrict__ bs,
        const unsigned short* __restrict__ Wnb, const float* __restrict__ bn,
        float* __restrict__ out, int N) {
    const int lane = threadIdx.x & 63;
    const int wid = (blockIdx.x * blockDim.x + threadIdx.x) >> 6;
    const int l15 = lane & 15;
    const int quad = lane >> 4;
    const int nTiles = N >> 4;
    if (wid >= nTiles) return;
    const int m0 = wid << 4;

    bf16x8 bsf[4][2], bnf[4][2];
#pragma unroll
    for (int tt = 0; tt < 4; ++tt) {
        const int o = tt * 16 + l15;
#pragma unroll
        for (int h = 0; h < 2; ++h) {
            bsf[tt][h] = *(const bf16x8*)(Wsb + o * C + h * 32 + quad * 8);
            bnf[tt][h] = *(const bf16x8*)(Wnb + o * C + h * 32 + quad * 8);
        }
    }

    const int m = m0 + l15;
    bf16x8 ax[2], ag[2];
#pragma unroll
    for (int h = 0; h < 2; ++h) {
        ax[h] = *(const bf16x8*)(xb + (size_t)m * C + h * 32 + quad * 8);
        ag[h] = *(const bf16x8*)(aggb + (size_t)m * C + h * 32 + quad * 8);
    }

#pragma unroll
    for (int tt = 0; tt < 4; ++tt) {
        f32x4 acc = {0.f, 0.f, 0.f, 0.f};
        acc = __builtin_amdgcn_mfma_f32_16x16x32_bf16(ax[0], bsf[tt][0], acc, 0, 0, 0);
        acc = __builtin_amdgcn_mfma_f32_16x16x32_bf16(ax[1], bsf[tt][1], acc, 0, 0, 0);
        acc = __builtin_amdgcn_mfma_f32_16x16x32_bf16(ag[0], bnf[tt][0], acc, 0, 0, 0);
        acc = __builtin_amdgcn_mfma_f32_16x16x32_bf16(ag[1], bnf[tt][1], acc, 0, 0, 0);
        const int o = tt * 16 + l15;
        const float bias = bs[o] + bn[o];
#pragma unroll
        for (int r = 0; r < 4; ++r)
            out[(m0 + quad * 4 + r) * C + o] = acc[r] + bias;
    }
}

extern "C" void kernel_launch(void* const* d_in, const int* in_sizes, int n_in,
                              void* d_out, int out_size, void* d_ws, size_t ws_size,
                              hipStream_t stream) {
    const float* x  = (const float*)d_in[0];
    const int*   ei = (const int*)d_in[1];
    const float* ew = (const float*)d_in[2];
    const float* Ws = (const float*)d_in[3];
    const float* bs = (const float*)d_in[4];
    const float* Wn = (const float*)d_in[5];
    const float* bn = (const float*)d_in[6];

    const int N = in_sizes[0] / C;   // 100000
    const int E = in_sizes[2];       // 1600000
    const int NBK = (N + BKT - 1) / BKT;   // 782

    char* p = (char*)d_ws;
    float* agg = (float*)p;                  p += (size_t)N * C * sizeof(float);  // 25.6MB
    unsigned short* xb = (unsigned short*)p;  p += (size_t)N * C * sizeof(short); // 12.8MB
    unsigned short* aggb = (unsigned short*)p; p += (size_t)N * C * sizeof(short);// 12.8MB
    int2* sorted = (int2*)p;                 p += (size_t)E * sizeof(int2);       // 12.8MB
    unsigned short* Wsb = (unsigned short*)p; p += (size_t)C * C * sizeof(short); // 8KB
    unsigned short* Wnb = (unsigned short*)p; p += (size_t)C * C * sizeof(short); // 8KB
    int* bhist = (int*)p;                    p += (size_t)MAXB * sizeof(int);
    int* boffs = (int*)p;                    p += (size_t)(MAXB + 1) * sizeof(int);
    int* bcur = (int*)p;                     p += (size_t)MAXB * sizeof(int);
    const size_t needed = (size_t)(p - (char*)d_ws);

    const int nTiles = N / 16;
    const int projBlocks = (nTiles + 3) / 4;

    if (needed <= ws_size && N <= (1 << 17) && NBK <= MAXB) {
        const int n4 = N * C / 4;
        hipMemsetAsync(bhist, 0, (size_t)NBK * sizeof(int), stream);
        prep_kernel<<<1024, 256, 0, stream>>>(ei, bhist, E, NBK, x, xb, n4,
                                              Ws, Wn, Wsb, Wnb);
        scan_kernel<<<1, 1024, 0, stream>>>(bhist, boffs, bcur, NBK);
        bin_kernel<<<(E + BINT - 1) / BINT, BTHR, 0, stream>>>(ei, ew, bcur,
                                                               sorted, E, NBK);
        agg_kernel<<<NBK, 512, 0, stream>>>(xb, sorted, boffs, agg, aggb, N);
        projb_kernel<<<projBlocks, 256, 0, stream>>>(xb, aggb, Wsb, bs, Wnb, bn,
                                                     (float*)d_out, N);
    } else {
        hipMemsetAsync(agg, 0, (size_t)N * C * sizeof(float), stream);
        scatter_kernel<<<2048, 256, 0, stream>>>(x, ei, ew, agg, E);
        proj_kernel<<<projBlocks, 256, 0, stream>>>(x, agg, Ws, bs, Wn, bn,
                                                    (float*)d_out, N);
    }
}

// Round 10
// 202.477 us; speedup vs baseline: 1.0228x; 1.0228x over previous
//
#include <hip/hip_runtime.h>
#include <hip/hip_bf16.h>

// SAGEConv: out = x @ W_self^T + b_self + segsum(x[col]*w, row) @ W_neigh^T + b_neigh
// N=100000, E=1600000, C=64. fp32 tensors; edge_index int32 [2*E] (dst|src); out fp32.
//
// R10: fine LDS sort + register accumulation (zero fp32 atomics), agg 696->64us.
// R11: bin rebuilt (1024 thr, stageb[] kills binary search, shfl scan): 43->~25us.
// R13: agg eighth-wave gather, reduce-scatter, bf16 end-to-end: 215->195us. <-- best
// R14/R15: proj-into-agg fusion: REGRESSED (epilogue latency / VGPR occupancy).
// R16: conv-in-bin: +5us (bin's 1 block/CU makes the conv tail serial).
// R17-R19: paired-row gather: REGRESSED (VGPR 32 under (512,8) cap -> compiler
//      serialized the 4 gathers; MLP stayed 2, overhead grew; agg 35->47).
// R20: agg reverted to R13/R16 single-row structure (VGPR ~44, unroll-2).
//      bin: BINT 6144->3072 (LDS 70->40KB, grid 261->521 = 2 blocks/CU,
//      32 waves/CU) -- bin is latency-bound at 1 block/CU; double the TLP.

#define C 64
#define BKT 128                 // nodes per bucket
#define MAXB 800                // max bucket count supported by static LDS
#define BINT 3072               // edges per bin block (R20: halved for 2 blk/CU)
#define BTHR 1024               // bin threads per block (16 waves)
#define CAP 2560                // agg: edges sorted per chunk (bucket avg 2046)

typedef __attribute__((ext_vector_type(8))) short bf16x8;
typedef __attribute__((ext_vector_type(4))) float f32x4;

__device__ inline unsigned short f2bf(float f) {
    union { __hip_bfloat16 h; unsigned short u; } c;
    c.h = __float2bfloat16(f);
    return c.u;
}

__device__ inline float bflo16(unsigned int u) {
    return __int_as_float((int)(u << 16));
}
__device__ inline float bfhi16(unsigned int u) {
    return __int_as_float((int)(u & 0xFFFF0000u));
}

// --------------------------------------------------------------------------
// prep: bucket histogram (LDS pre-agg) + x -> bf16 + weights -> bf16.
// --------------------------------------------------------------------------
__global__ __launch_bounds__(256) void prep_kernel(
        const int* __restrict__ ei, int* __restrict__ bhist, int E, int NBK,
        const float* __restrict__ x, unsigned short* __restrict__ xb, int n4,
        const float* __restrict__ Ws, const float* __restrict__ Wn,
        unsigned short* __restrict__ Wsb, unsigned short* __restrict__ Wnb) {
    __shared__ int lh[MAXB];
    const int t = threadIdx.x;
    for (int i = t; i < NBK; i += 256) lh[i] = 0;
    __syncthreads();
    const int gtid = blockIdx.x * 256 + t;
    const int gs = gridDim.x * 256;
    for (int e = gtid; e < E; e += gs)
        atomicAdd(&lh[ei[e] >> 7], 1);
    __syncthreads();
    for (int i = t; i < NBK; i += 256)
        if (lh[i]) atomicAdd(&bhist[i], lh[i]);
    const float4* x4 = (const float4*)x;
    ushort4* xb4 = (ushort4*)xb;
    for (int i = gtid; i < n4; i += gs) {
        float4 v = x4[i];
        ushort4 o;
        o.x = f2bf(v.x); o.y = f2bf(v.y); o.z = f2bf(v.z); o.w = f2bf(v.w);
        xb4[i] = o;
    }
    if (gtid < 1024) {   // 64*64 floats = 1024 float4 per weight matrix
        float4 v = ((const float4*)Ws)[gtid];
        ushort4 o;
        o.x = f2bf(v.x); o.y = f2bf(v.y); o.z = f2bf(v.z); o.w = f2bf(v.w);
        ((ushort4*)Wsb)[gtid] = o;
        v = ((const float4*)Wn)[gtid];
        o.x = f2bf(v.x); o.y = f2bf(v.y); o.z = f2bf(v.z); o.w = f2bf(v.w);
        ((ushort4*)Wnb)[gtid] = o;
    }
}

// --------------------------------------------------------------------------
// scan: exclusive scan of bhist[NBK] -> boffs[NBK+1], copy to bcur. 1 block.
// --------------------------------------------------------------------------
__global__ __launch_bounds__(1024) void scan_kernel(
        const int* __restrict__ bhist, int* __restrict__ boffs,
        int* __restrict__ bcur, int NBK) {
    __shared__ int s[1024];
    const int t = threadIdx.x;
    s[t] = (t < NBK) ? bhist[t] : 0;
    __syncthreads();
    for (int off = 1; off < 1024; off <<= 1) {
        int v = 0;
        if (t >= off) v = s[t - off];
        __syncthreads();
        if (t >= off) s[t] += v;
        __syncthreads();
    }
    if (t < NBK) {
        int e = (t > 0) ? s[t - 1] : 0;
        boffs[t] = e;
        bcur[t] = e;
        if (t == NBK - 1) boffs[NBK] = s[t];
    }
}

// --------------------------------------------------------------------------
// bin: coarse counting sort by 128-node bucket, LDS-staged coalesced writes.
// R20: BINT=3072 -> LDS ~40KB, 2 blocks/CU, 32 waves/CU (was 1 blk, 16 wv).
// --------------------------------------------------------------------------
__global__ __launch_bounds__(BTHR) void bin_kernel(
        const int* __restrict__ ei, const float* __restrict__ ew,
        int* __restrict__ bcur,
        int2* __restrict__ sorted, int E, int NBK) {
    __shared__ int2 stage[BINT];                 // 24 KB
    __shared__ unsigned short stageb[BINT];      // 6 KB
    __shared__ int h[MAXB];                      // histogram
    __shared__ int cur[MAXB];                    // running scatter cursor
    __shared__ int adj[MAXB];                    // globalBase - localStart
    __shared__ int wsum[16];

    const int t = threadIdx.x;
    const int lane = t & 63;
    const int wv = t >> 6;                       // 0..15
    const int e0 = blockIdx.x * BINT;
    const int cnt = min(BINT, E - e0);

    for (int i = t; i < NBK; i += BTHR) h[i] = 0;
    __syncthreads();

    // pass 1: histogram of bucket ids
#pragma unroll
    for (int k = 0; k < BINT / BTHR; ++k) {
        const int idx = t + k * BTHR;
        if (idx < cnt) atomicAdd(&h[ei[e0 + idx] >> 7], 1);
    }
    __syncthreads();

    // exclusive scan of h[0..NBK): wave shfl scan + 16-entry combine.
    const int val = (t < NBK) ? h[t] : 0;
    int v = val;
#pragma unroll
    for (int off = 1; off < 64; off <<= 1) {
        const int u = __shfl_up(v, off);
        if (lane >= off) v += u;
    }
    if (lane == 63) wsum[wv] = v;
    __syncthreads();
    if (t < 64) {
        int s = (lane < 16) ? wsum[lane] : 0;
#pragma unroll
        for (int off = 1; off < 16; off <<= 1) {
            const int u = __shfl_up(s, off);
            if (lane >= off) s += u;
        }
        if (lane < 16) wsum[lane] = s;           // inclusive wave-sum scan
    }
    __syncthreads();
    if (t < NBK) {
        const int incl = v + ((wv > 0) ? wsum[wv - 1] : 0);
        const int excl = incl - val;
        cur[t] = excl;
        const int g = val ? atomicAdd(&bcur[t], val) : 0;
        adj[t] = g - excl;
    }
    __syncthreads();

    // pass 2: LDS scatter into bucket-sorted order, recording bucket id
#pragma unroll
    for (int k = 0; k < BINT / BTHR; ++k) {
        const int idx = t + k * BTHR;
        if (idx < cnt) {
            const int e = e0 + idx;
            const int d = ei[e];
            const int s = ei[E + e];
            const float w = ew[e];
            const int b = d >> 7;
            const int dl = d & 127;
            const int p = atomicAdd(&cur[b], 1);
            stage[p] = make_int2((dl << 17) | s, __float_as_int(w));
            stageb[p] = (unsigned short)b;
        }
    }
    __syncthreads();

    // write-out: coalesced within each bucket run; no search needed
    for (int i = t; i < cnt; i += BTHR) {
        const int b = stageb[i];
        sorted[adj[b] + i] = stage[i];
    }
}

// --------------------------------------------------------------------------
// agg (R13/R16 verified structure): one block (512 thr, 8 waves) per bucket.
// Fine counting sort in LDS (3-barrier shfl scan), eighth-wave gather
// (8 lanes x uint4 = 16B/lane, 8 edges/wave concurrent, unroll-2 -> 16
// gathers in flight per wave), 7-shuffle reduce-scatter (lane owns 1
// channel), coalesced bf16 row write. fp32 agg = multi-chunk spill only.
// --------------------------------------------------------------------------
__global__ __launch_bounds__(512) void agg_kernel(
        const unsigned short* __restrict__ xb,   // bf16, row stride 64
        const int2* __restrict__ sorted,
        const int* __restrict__ boffs,
        float* __restrict__ agg,                 // fp32 spill (multi-chunk only)
        unsigned short* __restrict__ aggb,       // bf16 output
        int N) {
    __shared__ int2 meta2[CAP];             // 20 KB
    __shared__ int lcnt[BKT];
    __shared__ int lincl[BKT];
    __shared__ int lcur[BKT];

    const int t = threadIdx.x;
    const int b = blockIdx.x;
    const int node0 = b << 7;
    const int lane = t & 63;
    const int wv = t >> 6;                  // 0..7
    const int oct = lane >> 3;              // edge slot 0..7
    const int co = lane & 7;                // uint4 index within row

    const bool h1 = (lane & 8) != 0;
    const bool h2 = (lane & 16) != 0;
    const bool h3 = (lane & 32) != 0;
    // channel this lane owns after reduce-scatter
    const int ch = co * 8 + (h1 ? 4 : 0) + (h2 ? 2 : 0) + (h3 ? 1 : 0);

    const uint4* xb8 = (const uint4*)xb;    // row stride 8 uint4

    const int beg = boffs[b];
    const int end = boffs[b + 1];

    int chunk = beg;
    do {
        const int cc = (end - chunk < CAP) ? (end - chunk) : CAP;  // may be 0

        for (int i = t; i < BKT; i += 512) lcnt[i] = 0;
        __syncthreads();

        // pass 1: histogram of local dst (coalesced global reads)
        for (int i = t; i < cc; i += 512)
            atomicAdd(&lcnt[sorted[chunk + i].x >> 17], 1);
        __syncthreads();

        // 128-entry inclusive scan: 2-wave shfl scan + combine (3 barriers)
        if (t < BKT) {
            int acc = lcnt[t];
#pragma unroll
            for (int off = 1; off < 64; off <<= 1) {
                const int u = __shfl_up(acc, off);
                if (lane >= off) acc += u;
            }
            lincl[t] = acc;
        }
        __syncthreads();
        if (t >= 64 && t < BKT) lincl[t] += lincl[63];
        __syncthreads();
        if (t < BKT) lcur[t] = lincl[t] - lcnt[t];   // exclusive start
        __syncthreads();

        // pass 2: LDS scatter into fine-sorted order (src, w)
        for (int i = t; i < cc; i += 512) {
            const int2 m = sorted[chunk + i];
            const int dl = m.x >> 17;
            const int p = atomicAdd(&lcur[dl], 1);
            meta2[p] = make_int2(m.x & 0x1FFFF, m.y);
        }
        __syncthreads();

        const bool first = (chunk == beg);
        const bool last = (chunk + CAP >= end);

        // aggregate: wave wv handles rows wv, wv+8, ... (16 rows)
        for (int r = wv; r < BKT; r += 8) {
            const int s1 = lincl[r];
            const int s0 = s1 - lcnt[r];
            float a0 = 0.f, a1 = 0.f, a2 = 0.f, a3 = 0.f;
            float a4 = 0.f, a5 = 0.f, a6 = 0.f, a7 = 0.f;
            int j = s0 + oct;
            // unroll-2: both gathers issued before either's FMAs
            for (; j + 8 < s1; j += 16) {
                const int2 m0 = meta2[j];
                const int2 m1 = meta2[j + 8];
                const uint4 u0 = xb8[(unsigned)m0.x * 8u + co];
                const uint4 u1 = xb8[(unsigned)m1.x * 8u + co];
                const float w0 = __int_as_float(m0.y);
                const float w1 = __int_as_float(m1.y);
                a0 += w0 * bflo16(u0.x); a1 += w0 * bfhi16(u0.x);
                a2 += w0 * bflo16(u0.y); a3 += w0 * bfhi16(u0.y);
                a4 += w0 * bflo16(u0.z); a5 += w0 * bfhi16(u0.z);
                a6 += w0 * bflo16(u0.w); a7 += w0 * bfhi16(u0.w);
                a0 += w1 * bflo16(u1.x); a1 += w1 * bfhi16(u1.x);
                a2 += w1 * bflo16(u1.y); a3 += w1 * bfhi16(u1.y);
                a4 += w1 * bflo16(u1.z); a5 += w1 * bfhi16(u1.z);
                a6 += w1 * bflo16(u1.w); a7 += w1 * bfhi16(u1.w);
            }
            if (j < s1) {
                const int2 m0 = meta2[j];
                const uint4 u0 = xb8[(unsigned)m0.x * 8u + co];
                const float w0 = __int_as_float(m0.y);
                a0 += w0 * bflo16(u0.x); a1 += w0 * bfhi16(u0.x);
                a2 += w0 * bflo16(u0.y); a3 += w0 * bfhi16(u0.y);
                a4 += w0 * bflo16(u0.z); a5 += w0 * bfhi16(u0.z);
                a6 += w0 * bflo16(u0.w); a7 += w0 * bfhi16(u0.w);
            }
            // reduce-scatter across octs (7 shuffles total)
            float r0 = __shfl_xor(h1 ? a0 : a4, 8);
            float r1 = __shfl_xor(h1 ? a1 : a5, 8);
            float r2 = __shfl_xor(h1 ? a2 : a6, 8);
            float r3 = __shfl_xor(h1 ? a3 : a7, 8);
            const float b0 = (h1 ? a4 : a0) + r0;
            const float b1 = (h1 ? a5 : a1) + r1;
            const float b2 = (h1 ? a6 : a2) + r2;
            const float b3 = (h1 ? a7 : a3) + r3;
            float r4 = __shfl_xor(h2 ? b0 : b2, 16);
            float r5 = __shfl_xor(h2 ? b1 : b3, 16);
            const float c0 = (h2 ? b2 : b0) + r4;
            const float c1 = (h2 ? b3 : b1) + r5;
            float r6 = __shfl_xor(h3 ? c0 : c1, 32);
            float vfin = (h3 ? c1 : c0) + r6;

            const int node = node0 + r;
            if (node < N) {
                const size_t off = (size_t)node * C + ch;
                if (last) {
                    if (!first) vfin += agg[off];
                    aggb[off] = f2bf(vfin);
                } else {
                    if (first) agg[off] = vfin;
                    else       agg[off] += vfin;
                }
            }
        }
        chunk += CAP;
        __syncthreads();            // protect lcnt reuse next chunk
    } while (chunk < end);
}

// --------------------------------------------------------------------------
// fallback (ws too small / N too big): R2 atomic scatter + fp32 proj.
// --------------------------------------------------------------------------
__global__ __launch_bounds__(256) void scatter_kernel(
        const float* __restrict__ x, const int* __restrict__ ei,
        const float* __restrict__ ew, float* __restrict__ agg, int E) {
    const int lane = threadIdx.x & 63;
    const int wid = (blockIdx.x * blockDim.x + threadIdx.x) >> 6;
    const int nw = (gridDim.x * blockDim.x) >> 6;
    for (int base = wid * 64; base < E; base += nw * 64) {
        const int e = base + lane;
        int dst = 0, src = 0; float w = 0.f;
        if (e < E) { dst = ei[e]; src = ei[E + e]; w = ew[e]; }
        const int cnt = min(64, E - base);
        for (int j = 0; j < cnt; ++j) {
            const int d = __shfl(dst, j);
            const int s = __shfl(src, j);
            const float wj = __shfl(w, j);
            atomicAdd(&agg[d * C + lane], x[s * C + lane] * wj);
        }
    }
}

__device__ inline bf16x8 cvt8(const float* __restrict__ p) {
    f32x4 lo = *(const f32x4*)p;
    f32x4 hi = *(const f32x4*)(p + 4);
    union { bf16x8 v; __hip_bfloat16 e[8]; } u;
#pragma unroll
    for (int j = 0; j < 4; ++j) u.e[j] = __float2bfloat16(lo[j]);
#pragma unroll
    for (int j = 0; j < 4; ++j) u.e[4 + j] = __float2bfloat16(hi[j]);
    return u.v;
}

__global__ __launch_bounds__(256) void proj_kernel(
        const float* __restrict__ x, const float* __restrict__ agg,
        const float* __restrict__ Ws, const float* __restrict__ bs,
        const float* __restrict__ Wn, const float* __restrict__ bn,
        float* __restrict__ out, int N) {
    const int lane = threadIdx.x & 63;
    const int wid = (blockIdx.x * blockDim.x + threadIdx.x) >> 6;
    const int l15 = lane & 15;
    const int quad = lane >> 4;
    const int nTiles = N >> 4;
    if (wid >= nTiles) return;
    const int m0 = wid << 4;

    bf16x8 bsf[4][2], bnf[4][2];
#pragma unroll
    for (int tt = 0; tt < 4; ++tt) {
        const int o = tt * 16 + l15;
#pragma unroll
        for (int h = 0; h < 2; ++h) {
            bsf[tt][h] = cvt8(Ws + o * C + h * 32 + quad * 8);
            bnf[tt][h] = cvt8(Wn + o * C + h * 32 + quad * 8);
        }
    }

    const int m = m0 + l15;
    bf16x8 ax[2], ag[2];
#pragma unroll
    for (int h = 0; h < 2; ++h) {
        ax[h] = cvt8(x + m * C + h * 32 + quad * 8);
        ag[h] = cvt8(agg + m * C + h * 32 + quad * 8);
    }

#pragma unroll
    for (int tt = 0; tt < 4; ++tt) {
        f32x4 acc = {0.f, 0.f, 0.f, 0.f};
        acc = __builtin_amdgcn_mfma_f32_16x16x32_bf16(ax[0], bsf[tt][0], acc, 0, 0, 0);
        acc = __builtin_amdgcn_mfma_f32_16x16x32_bf16(ax[1], bsf[tt][1], acc, 0, 0, 0);
        acc = __builtin_amdgcn_mfma_f32_16x16x32_bf16(ag[0], bnf[tt][0], acc, 0, 0, 0);
        acc = __builtin_amdgcn_mfma_f32_16x16x32_bf16(ag[1], bnf[tt][1], acc, 0, 0, 0);
        const int o = tt * 16 + l15;
        const float bias = bs[o] + bn[o];
#pragma unroll
        for (int r = 0; r < 4; ++r)
            out[(m0 + quad * 4 + r) * C + o] = acc[r] + bias;
    }
}

// --------------------------------------------------------------------------
// projb: main-path proj. All operands already bf16 (xb, aggb, Wsb, Wnb) ->
// pure 16B loads + MFMA, no conversions. HBM: 12.8+12.8 read, 25.6 write.
// --------------------------------------------------------------------------
__global__ __launch_bounds__(256) void projb_kernel(
        const unsigned short* __restrict__ xb,
        const unsigned short* __restrict__ aggb,
        const unsigned short* __restrict__ Wsb, const float* __restrict__ bs,
        const unsigned short* __restrict__ Wnb, const float* __restrict__ bn,
        float* __restrict__ out, int N) {
    const int lane = threadIdx.x & 63;
    const int wid = (blockIdx.x * blockDim.x + threadIdx.x) >> 6;
    const int l15 = lane & 15;
    const int quad = lane >> 4;
    const int nTiles = N >> 4;
    if (wid >= nTiles) return;
    const int m0 = wid << 4;

    bf16x8 bsf[4][2], bnf[4][2];
#pragma unroll
    for (int tt = 0; tt < 4; ++tt) {
        const int o = tt * 16 + l15;
#pragma unroll
        for (int h = 0; h < 2; ++h) {
            bsf[tt][h] = *(const bf16x8*)(Wsb + o * C + h * 32 + quad * 8);
            bnf[tt][h] = *(const bf16x8*)(Wnb + o * C + h * 32 + quad * 8);
        }
    }

    const int m = m0 + l15;
    bf16x8 ax[2], ag[2];
#pragma unroll
    for (int h = 0; h < 2; ++h) {
        ax[h] = *(const bf16x8*)(xb + (size_t)m * C + h * 32 + quad * 8);
        ag[h] = *(const bf16x8*)(aggb + (size_t)m * C + h * 32 + quad * 8);
    }

#pragma unroll
    for (int tt = 0; tt < 4; ++tt) {
        f32x4 acc = {0.f, 0.f, 0.f, 0.f};
        acc = __builtin_amdgcn_mfma_f32_16x16x32_bf16(ax[0], bsf[tt][0], acc, 0, 0, 0);
        acc = __builtin_amdgcn_mfma_f32_16x16x32_bf16(ax[1], bsf[tt][1], acc, 0, 0, 0);
        acc = __builtin_amdgcn_mfma_f32_16x16x32_bf16(ag[0], bnf[tt][0], acc, 0, 0, 0);
        acc = __builtin_amdgcn_mfma_f32_16x16x32_bf16(ag[1], bnf[tt][1], acc, 0, 0, 0);
        const int o = tt * 16 + l15;
        const float bias = bs[o] + bn[o];
#pragma unroll
        for (int r = 0; r < 4; ++r)
            out[(m0 + quad * 4 + r) * C + o] = acc[r] + bias;
    }
}

extern "C" void kernel_launch(void* const* d_in, const int* in_sizes, int n_in,
                              void* d_out, int out_size, void* d_ws, size_t ws_size,
                              hipStream_t stream) {
    const float* x  = (const float*)d_in[0];
    const int*   ei = (const int*)d_in[1];
    const float* ew = (const float*)d_in[2];
    const float* Ws = (const float*)d_in[3];
    const float* bs = (const float*)d_in[4];
    const float* Wn = (const float*)d_in[5];
    const float* bn = (const float*)d_in[6];

    const int N = in_sizes[0] / C;   // 100000
    const int E = in_sizes[2];       // 1600000
    const int NBK = (N + BKT - 1) / BKT;   // 782

    char* p = (char*)d_ws;
    float* agg = (float*)p;                  p += (size_t)N * C * sizeof(float);  // 25.6MB
    unsigned short* xb = (unsigned short*)p;  p += (size_t)N * C * sizeof(short); // 12.8MB
    unsigned short* aggb = (unsigned short*)p; p += (size_t)N * C * sizeof(short);// 12.8MB
    int2* sorted = (int2*)p;                 p += (size_t)E * sizeof(int2);       // 12.8MB
    unsigned short* Wsb = (unsigned short*)p; p += (size_t)C * C * sizeof(short); // 8KB
    unsigned short* Wnb = (unsigned short*)p; p += (size_t)C * C * sizeof(short); // 8KB
    int* bhist = (int*)p;                    p += (size_t)MAXB * sizeof(int);
    int* boffs = (int*)p;                    p += (size_t)(MAXB + 1) * sizeof(int);
    int* bcur = (int*)p;                     p += (size_t)MAXB * sizeof(int);
    const size_t needed = (size_t)(p - (char*)d_ws);

    const int nTiles = N / 16;
    const int projBlocks = (nTiles + 3) / 4;

    if (needed <= ws_size && N <= (1 << 17) && NBK <= MAXB) {
        const int n4 = N * C / 4;
        hipMemsetAsync(bhist, 0, (size_t)NBK * sizeof(int), stream);
        prep_kernel<<<1024, 256, 0, stream>>>(ei, bhist, E, NBK, x, xb, n4,
                                              Ws, Wn, Wsb, Wnb);
        scan_kernel<<<1, 1024, 0, stream>>>(bhist, boffs, bcur, NBK);
        bin_kernel<<<(E + BINT - 1) / BINT, BTHR, 0, stream>>>(ei, ew, bcur,
                                                               sorted, E, NBK);
        agg_kernel<<<NBK, 512, 0, stream>>>(xb, sorted, boffs, agg, aggb, N);
        projb_kernel<<<projBlocks, 256, 0, stream>>>(xb, aggb, Wsb, bs, Wnb, bn,
                                                     (float*)d_out, N);
    } else {
        hipMemsetAsync(agg, 0, (size_t)N * C * sizeof(float), stream);
        scatter_kernel<<<2048, 256, 0, stream>>>(x, ei, ew, agg, E);
        proj_kernel<<<projBlocks, 256, 0, stream>>>(x, agg, Ws, bs, Wn, bn,
                                                    (float*)d_out, N);
    }
}

// Round 11
// 194.109 us; speedup vs baseline: 1.0669x; 1.0431x over previous
//
#include <hip/hip_runtime.h>
#include <hip/hip_bf16.h>

// SAGEConv: out = x @ W_self^T + b_self + segsum(x[col]*w, row) @ W_neigh^T + b_neigh
// N=100000, E=1600000, C=64. fp32 tensors; edge_index int32 [2*E] (dst|src); out fp32.
//
// R10: fine LDS sort + register accumulation (zero fp32 atomics), agg 696->64us.
// R11: bin rebuilt (1024 thr, stageb[] kills binary search, shfl scan): 43->~25us.
// R13: agg eighth-wave gather (8 lanes x uint4, 16 in flight), reduce-scatter,
//      bf16 pipeline end-to-end: 215->195us.  <-- BEST MEASURED (194.8us)
// R14/R15: proj-into-agg fusion: REGRESSED (epilogue latency / VGPR occupancy).
// R16: conv-in-bin + agg shfl-scan: 199.9 (conv tail serial at 1 blk/CU).
// R17-R19: paired-row gather: REGRESSED (compiler serialized gathers under
//      VGPR cap; MLP stayed 2, overhead grew; agg 35->47us).
// R20: BINT 3072: REGRESSED (bin's per-block NBK-fixed cost -- 782-entry
//      zero+scan+atomics -- doubled with block count; 202.5us).
// R21: exact R13 restore. Every structural variation since R13 regressed or
//      was neutral; agg gather is at its L3-latency/ILP/occupancy sweet spot
//      (VGPR 44, unroll-2), bin amortizes fixed cost best at BINT=6144.

#define C 64
#define BKT 128                 // nodes per bucket
#define MAXB 800                // max bucket count supported by static LDS
#define BINT 6144               // edges per bin block
#define BTHR 1024               // bin threads per block (16 waves)
#define CAP 2560                // agg: edges sorted per chunk (bucket avg 2046)

typedef __attribute__((ext_vector_type(8))) short bf16x8;
typedef __attribute__((ext_vector_type(4))) float f32x4;

__device__ inline unsigned short f2bf(float f) {
    union { __hip_bfloat16 h; unsigned short u; } c;
    c.h = __float2bfloat16(f);
    return c.u;
}

__device__ inline float bflo16(unsigned int u) {
    return __int_as_float((int)(u << 16));
}
__device__ inline float bfhi16(unsigned int u) {
    return __int_as_float((int)(u & 0xFFFF0000u));
}

// --------------------------------------------------------------------------
// prep: bucket histogram (LDS pre-agg) + x -> bf16 + weights -> bf16.
// --------------------------------------------------------------------------
__global__ __launch_bounds__(256) void prep_kernel(
        const int* __restrict__ ei, int* __restrict__ bhist, int E, int NBK,
        const float* __restrict__ x, unsigned short* __restrict__ xb, int n4,
        const float* __restrict__ Ws, const float* __restrict__ Wn,
        unsigned short* __restrict__ Wsb, unsigned short* __restrict__ Wnb) {
    __shared__ int lh[MAXB];
    const int t = threadIdx.x;
    for (int i = t; i < NBK; i += 256) lh[i] = 0;
    __syncthreads();
    const int gtid = blockIdx.x * 256 + t;
    const int gs = gridDim.x * 256;
    for (int e = gtid; e < E; e += gs)
        atomicAdd(&lh[ei[e] >> 7], 1);
    __syncthreads();
    for (int i = t; i < NBK; i += 256)
        if (lh[i]) atomicAdd(&bhist[i], lh[i]);
    const float4* x4 = (const float4*)x;
    ushort4* xb4 = (ushort4*)xb;
    for (int i = gtid; i < n4; i += gs) {
        float4 v = x4[i];
        ushort4 o;
        o.x = f2bf(v.x); o.y = f2bf(v.y); o.z = f2bf(v.z); o.w = f2bf(v.w);
        xb4[i] = o;
    }
    // weights: 64*64 floats each = 1024 float4
    if (gtid < 1024) {
        float4 v = ((const float4*)Ws)[gtid];
        ushort4 o;
        o.x = f2bf(v.x); o.y = f2bf(v.y); o.z = f2bf(v.z); o.w = f2bf(v.w);
        ((ushort4*)Wsb)[gtid] = o;
        v = ((const float4*)Wn)[gtid];
        o.x = f2bf(v.x); o.y = f2bf(v.y); o.z = f2bf(v.z); o.w = f2bf(v.w);
        ((ushort4*)Wnb)[gtid] = o;
    }
}

// --------------------------------------------------------------------------
// scan: exclusive scan of bhist[NBK] -> boffs[NBK+1], copy to bcur. 1 block.
// --------------------------------------------------------------------------
__global__ __launch_bounds__(1024) void scan_kernel(
        const int* __restrict__ bhist, int* __restrict__ boffs,
        int* __restrict__ bcur, int NBK) {
    __shared__ int s[1024];
    const int t = threadIdx.x;
    s[t] = (t < NBK) ? bhist[t] : 0;
    __syncthreads();
    for (int off = 1; off < 1024; off <<= 1) {
        int v = 0;
        if (t >= off) v = s[t - off];
        __syncthreads();
        if (t >= off) s[t] += v;
        __syncthreads();
    }
    if (t < NBK) {
        int e = (t > 0) ? s[t - 1] : 0;
        boffs[t] = e;
        bcur[t] = e;
        if (t == NBK - 1) boffs[NBK] = s[t];
    }
}

// --------------------------------------------------------------------------
// bin: coarse counting sort by 128-node bucket, LDS-staged coalesced writes.
// 1024 threads (16 waves); shfl_up wave scan; bucket id stored per staged
// edge -> direct final address (adj[b] + i), no binary search.
// --------------------------------------------------------------------------
__global__ __launch_bounds__(BTHR) void bin_kernel(
        const int* __restrict__ ei, const float* __restrict__ ew,
        int* __restrict__ bcur, const int* __restrict__ unused,
        int2* __restrict__ sorted, int E, int NBK) {
    __shared__ int2 stage[BINT];                 // 48 KB
    __shared__ unsigned short stageb[BINT];      // 12 KB
    __shared__ int h[MAXB];                      // histogram
    __shared__ int cur[MAXB];                    // running scatter cursor
    __shared__ int adj[MAXB];                    // globalBase - localStart
    __shared__ int wsum[16];

    const int t = threadIdx.x;
    const int lane = t & 63;
    const int wv = t >> 6;                       // 0..15
    const int e0 = blockIdx.x * BINT;
    const int cnt = min(BINT, E - e0);

    for (int i = t; i < NBK; i += BTHR) h[i] = 0;
    __syncthreads();

    // pass 1: histogram of bucket ids
#pragma unroll
    for (int k = 0; k < BINT / BTHR; ++k) {
        const int idx = t + k * BTHR;
        if (idx < cnt) atomicAdd(&h[ei[e0 + idx] >> 7], 1);
    }
    __syncthreads();

    // exclusive scan of h[0..NBK) across 1024 threads: wave shfl scan +
    // 16-entry cross-wave combine. (NBK <= 800 <= 1024: 1 value/thread.)
    const int val = (t < NBK) ? h[t] : 0;
    int v = val;
#pragma unroll
    for (int off = 1; off < 64; off <<= 1) {
        const int u = __shfl_up(v, off);
        if (lane >= off) v += u;
    }
    if (lane == 63) wsum[wv] = v;
    __syncthreads();
    if (t < 64) {
        int s = (lane < 16) ? wsum[lane] : 0;
#pragma unroll
        for (int off = 1; off < 16; off <<= 1) {
            const int u = __shfl_up(s, off);
            if (lane >= off) s += u;
        }
        if (lane < 16) wsum[lane] = s;           // inclusive wave-sum scan
    }
    __syncthreads();
    if (t < NBK) {
        const int incl = v + ((wv > 0) ? wsum[wv - 1] : 0);
        const int excl = incl - val;
        cur[t] = excl;
        const int g = val ? atomicAdd(&bcur[t], val) : 0;
        adj[t] = g - excl;
    }
    __syncthreads();

    // pass 2: LDS scatter into bucket-sorted order, recording bucket id
#pragma unroll
    for (int k = 0; k < BINT / BTHR; ++k) {
        const int idx = t + k * BTHR;
        if (idx < cnt) {
            const int e = e0 + idx;
            const int d = ei[e];
            const int s = ei[E + e];
            const float w = ew[e];
            const int b = d >> 7;
            const int dl = d & 127;
            const int p = atomicAdd(&cur[b], 1);
            stage[p] = make_int2((dl << 17) | s, __float_as_int(w));
            stageb[p] = (unsigned short)b;
        }
    }
    __syncthreads();

    // write-out: coalesced within each bucket run; no search needed
    for (int i = t; i < cnt; i += BTHR) {
        const int b = stageb[i];
        sorted[adj[b] + i] = stage[i];
    }
}

// --------------------------------------------------------------------------
// agg v7: one block (512 thr, 8 waves) per bucket. Fine counting sort in
// LDS, then wave wv owns rows wv, wv+8, ... EIGHTH-wave per edge: 8 lanes x
// uint4 (16B/lane) = 128B row, 8 edges concurrent per wave, unroll-2 (16
// gathers in flight). 3-step reduce-scatter (7 shuffles) leaves each lane
// owning 1 channel -> coalesced 64-lane row write. Output bf16 (identical
// rounding to old proj cvt); fp32 agg used only as multi-chunk spill.
// --------------------------------------------------------------------------
__global__ __launch_bounds__(512) void agg_kernel(
        const unsigned short* __restrict__ xb,   // bf16, row stride 64
        const int2* __restrict__ sorted,
        const int* __restrict__ boffs,
        float* __restrict__ agg,                 // fp32 spill (multi-chunk only)
        unsigned short* __restrict__ aggb,       // bf16 output
        int N) {
    __shared__ int2 meta2[CAP];             // 20 KB
    __shared__ int lcnt[BKT];
    __shared__ int lincl[BKT];
    __shared__ int lcur[BKT];

    const int t = threadIdx.x;
    const int b = blockIdx.x;
    const int node0 = b << 7;
    const int lane = t & 63;
    const int wv = t >> 6;                  // 0..7
    const int oct = lane >> 3;              // edge slot 0..7
    const int co = lane & 7;                // uint4 index within row

    const bool h1 = (lane & 8) != 0;
    const bool h2 = (lane & 16) != 0;
    const bool h3 = (lane & 32) != 0;
    // channel this lane owns after reduce-scatter
    const int ch = co * 8 + (h1 ? 4 : 0) + (h2 ? 2 : 0) + (h3 ? 1 : 0);

    const uint4* xb8 = (const uint4*)xb;    // row stride 8 uint4

    const int beg = boffs[b];
    const int end = boffs[b + 1];

    int chunk = beg;
    do {
        const int cc = (end - chunk < CAP) ? (end - chunk) : CAP;  // may be 0

        for (int i = t; i < BKT; i += 512) lcnt[i] = 0;
        __syncthreads();

        // pass 1: histogram of local dst (coalesced global reads)
        for (int i = t; i < cc; i += 512)
            atomicAdd(&lcnt[sorted[chunk + i].x >> 17], 1);
        __syncthreads();

        // 128-entry inclusive scan (Hillis-Steele, threads 0..127)
        if (t < BKT) lincl[t] = lcnt[t];
        __syncthreads();
        for (int off = 1; off < BKT; off <<= 1) {
            int v = 0;
            if (t < BKT && t >= off) v = lincl[t - off];
            __syncthreads();
            if (t < BKT && t >= off) lincl[t] += v;
            __syncthreads();
        }
        if (t < BKT) lcur[t] = lincl[t] - lcnt[t];   // exclusive start
        __syncthreads();

        // pass 2: LDS scatter into fine-sorted order (src, w)
        for (int i = t; i < cc; i += 512) {
            const int2 m = sorted[chunk + i];
            const int dl = m.x >> 17;
            const int p = atomicAdd(&lcur[dl], 1);
            meta2[p] = make_int2(m.x & 0x1FFFF, m.y);
        }
        __syncthreads();

        const bool first = (chunk == beg);
        const bool last = (chunk + CAP >= end);

        // aggregate: wave wv handles rows wv, wv+8, ... (16 rows)
        for (int r = wv; r < BKT; r += 8) {
            const int s1 = lincl[r];
            const int s0 = s1 - lcnt[r];
            float a0 = 0.f, a1 = 0.f, a2 = 0.f, a3 = 0.f;
            float a4 = 0.f, a5 = 0.f, a6 = 0.f, a7 = 0.f;
            int j = s0 + oct;
            // unroll-2: both gathers issued before either's FMAs
            for (; j + 8 < s1; j += 16) {
                const int2 m0 = meta2[j];
                const int2 m1 = meta2[j + 8];
                const uint4 u0 = xb8[(unsigned)m0.x * 8u + co];
                const uint4 u1 = xb8[(unsigned)m1.x * 8u + co];
                const float w0 = __int_as_float(m0.y);
                const float w1 = __int_as_float(m1.y);
                a0 += w0 * bflo16(u0.x); a1 += w0 * bfhi16(u0.x);
                a2 += w0 * bflo16(u0.y); a3 += w0 * bfhi16(u0.y);
                a4 += w0 * bflo16(u0.z); a5 += w0 * bfhi16(u0.z);
                a6 += w0 * bflo16(u0.w); a7 += w0 * bfhi16(u0.w);
                a0 += w1 * bflo16(u1.x); a1 += w1 * bfhi16(u1.x);
                a2 += w1 * bflo16(u1.y); a3 += w1 * bfhi16(u1.y);
                a4 += w1 * bflo16(u1.z); a5 += w1 * bfhi16(u1.z);
                a6 += w1 * bflo16(u1.w); a7 += w1 * bfhi16(u1.w);
            }
            if (j < s1) {
                const int2 m0 = meta2[j];
                const uint4 u0 = xb8[(unsigned)m0.x * 8u + co];
                const float w0 = __int_as_float(m0.y);
                a0 += w0 * bflo16(u0.x); a1 += w0 * bfhi16(u0.x);
                a2 += w0 * bflo16(u0.y); a3 += w0 * bfhi16(u0.y);
                a4 += w0 * bflo16(u0.z); a5 += w0 * bfhi16(u0.z);
                a6 += w0 * bflo16(u0.w); a7 += w0 * bfhi16(u0.w);
            }
            // reduce-scatter across octs (7 shuffles total).
            // step 1, dist 8: keep = h1 ? a[k+4] : a[k]; send the other.
            float r0 = __shfl_xor(h1 ? a0 : a4, 8);
            float r1 = __shfl_xor(h1 ? a1 : a5, 8);
            float r2 = __shfl_xor(h1 ? a2 : a6, 8);
            float r3 = __shfl_xor(h1 ? a3 : a7, 8);
            const float b0 = (h1 ? a4 : a0) + r0;
            const float b1 = (h1 ? a5 : a1) + r1;
            const float b2 = (h1 ? a6 : a2) + r2;
            const float b3 = (h1 ? a7 : a3) + r3;
            // step 2, dist 16
            float r4 = __shfl_xor(h2 ? b0 : b2, 16);
            float r5 = __shfl_xor(h2 ? b1 : b3, 16);
            const float c0 = (h2 ? b2 : b0) + r4;
            const float c1 = (h2 ? b3 : b1) + r5;
            // step 3, dist 32
            float r6 = __shfl_xor(h3 ? c0 : c1, 32);
            float vfin = (h3 ? c1 : c0) + r6;

            const int node = node0 + r;
            if (node < N) {
                const size_t off = (size_t)node * C + ch;
                if (last) {
                    if (!first) vfin += agg[off];
                    aggb[off] = f2bf(vfin);
                } else {
                    if (first) agg[off] = vfin;
                    else       agg[off] += vfin;
                }
            }
        }
        chunk += CAP;
        __syncthreads();            // protect lcnt reuse next chunk
    } while (chunk < end);
}

// --------------------------------------------------------------------------
// fallback (ws too small / N too big): R2 atomic scatter + fp32 proj.
// --------------------------------------------------------------------------
__global__ __launch_bounds__(256) void scatter_kernel(
        const float* __restrict__ x, const int* __restrict__ ei,
        const float* __restrict__ ew, float* __restrict__ agg, int E) {
    const int lane = threadIdx.x & 63;
    const int wid = (blockIdx.x * blockDim.x + threadIdx.x) >> 6;
    const int nw = (gridDim.x * blockDim.x) >> 6;
    for (int base = wid * 64; base < E; base += nw * 64) {
        const int e = base + lane;
        int dst = 0, src = 0; float w = 0.f;
        if (e < E) { dst = ei[e]; src = ei[E + e]; w = ew[e]; }
        const int cnt = min(64, E - base);
        for (int j = 0; j < cnt; ++j) {
            const int d = __shfl(dst, j);
            const int s = __shfl(src, j);
            const float wj = __shfl(w, j);
            atomicAdd(&agg[d * C + lane], x[s * C + lane] * wj);
        }
    }
}

__device__ inline bf16x8 cvt8(const float* __restrict__ p) {
    f32x4 lo = *(const f32x4*)p;
    f32x4 hi = *(const f32x4*)(p + 4);
    union { bf16x8 v; __hip_bfloat16 e[8]; } u;
#pragma unroll
    for (int j = 0; j < 4; ++j) u.e[j] = __float2bfloat16(lo[j]);
#pragma unroll
    for (int j = 0; j < 4; ++j) u.e[4 + j] = __float2bfloat16(hi[j]);
    return u.v;
}

__global__ __launch_bounds__(256) void proj_kernel(
        const float* __restrict__ x, const float* __restrict__ agg,
        const float* __restrict__ Ws, const float* __restrict__ bs,
        const float* __restrict__ Wn, const float* __restrict__ bn,
        float* __restrict__ out, int N) {
    const int lane = threadIdx.x & 63;
    const int wid = (blockIdx.x * blockDim.x + threadIdx.x) >> 6;
    const int l15 = lane & 15;
    const int quad = lane >> 4;
    const int nTiles = N >> 4;
    if (wid >= nTiles) return;
    const int m0 = wid << 4;

    bf16x8 bsf[4][2], bnf[4][2];
#pragma unroll
    for (int tt = 0; tt < 4; ++tt) {
        const int o = tt * 16 + l15;
#pragma unroll
        for (int h = 0; h < 2; ++h) {
            bsf[tt][h] = cvt8(Ws + o * C + h * 32 + quad * 8);
            bnf[tt][h] = cvt8(Wn + o * C + h * 32 + quad * 8);
        }
    }

    const int m = m0 + l15;
    bf16x8 ax[2], ag[2];
#pragma unroll
    for (int h = 0; h < 2; ++h) {
        ax[h] = cvt8(x + m * C + h * 32 + quad * 8);
        ag[h] = cvt8(agg + m * C + h * 32 + quad * 8);
    }

#pragma unroll
    for (int tt = 0; tt < 4; ++tt) {
        f32x4 acc = {0.f, 0.f, 0.f, 0.f};
        acc = __builtin_amdgcn_mfma_f32_16x16x32_bf16(ax[0], bsf[tt][0], acc, 0, 0, 0);
        acc = __builtin_amdgcn_mfma_f32_16x16x32_bf16(ax[1], bsf[tt][1], acc, 0, 0, 0);
        acc = __builtin_amdgcn_mfma_f32_16x16x32_bf16(ag[0], bnf[tt][0], acc, 0, 0, 0);
        acc = __builtin_amdgcn_mfma_f32_16x16x32_bf16(ag[1], bnf[tt][1], acc, 0, 0, 0);
        const int o = tt * 16 + l15;
        const float bias = bs[o] + bn[o];
#pragma unroll
        for (int r = 0; r < 4; ++r)
            out[(m0 + quad * 4 + r) * C + o] = acc[r] + bias;
    }
}

// --------------------------------------------------------------------------
// projb: main-path proj. All operands already bf16 (xb, aggb, Wsb, Wnb) ->
// pure 16B loads + MFMA, no conversions. HBM: 12.8+12.8+0 read, 25.6 write.
// --------------------------------------------------------------------------
__global__ __launch_bounds__(256) void projb_kernel(
        const unsigned short* __restrict__ xb,
        const unsigned short* __restrict__ aggb,
        const unsigned short* __restrict__ Wsb, const float* __restrict__ bs,
        const unsigned short* __restrict__ Wnb, const float* __restrict__ bn,
        float* __restrict__ out, int N) {
    const int lane = threadIdx.x & 63;
    const int wid = (blockIdx.x * blockDim.x + threadIdx.x) >> 6;
    const int l15 = lane & 15;
    const int quad = lane >> 4;
    const int nTiles = N >> 4;
    if (wid >= nTiles) return;
    const int m0 = wid << 4;

    bf16x8 bsf[4][2], bnf[4][2];
#pragma unroll
    for (int tt = 0; tt < 4; ++tt) {
        const int o = tt * 16 + l15;
#pragma unroll
        for (int h = 0; h < 2; ++h) {
            bsf[tt][h] = *(const bf16x8*)(Wsb + o * C + h * 32 + quad * 8);
            bnf[tt][h] = *(const bf16x8*)(Wnb + o * C + h * 32 + quad * 8);
        }
    }

    const int m = m0 + l15;
    bf16x8 ax[2], ag[2];
#pragma unroll
    for (int h = 0; h < 2; ++h) {
        ax[h] = *(const bf16x8*)(xb + (size_t)m * C + h * 32 + quad * 8);
        ag[h] = *(const bf16x8*)(aggb + (size_t)m * C + h * 32 + quad * 8);
    }

#pragma unroll
    for (int tt = 0; tt < 4; ++tt) {
        f32x4 acc = {0.f, 0.f, 0.f, 0.f};
        acc = __builtin_amdgcn_mfma_f32_16x16x32_bf16(ax[0], bsf[tt][0], acc, 0, 0, 0);
        acc = __builtin_amdgcn_mfma_f32_16x16x32_bf16(ax[1], bsf[tt][1], acc, 0, 0, 0);
        acc = __builtin_amdgcn_mfma_f32_16x16x32_bf16(ag[0], bnf[tt][0], acc, 0, 0, 0);
        acc = __builtin_amdgcn_mfma_f32_16x16x32_bf16(ag[1], bnf[tt][1], acc, 0, 0, 0);
        const int o = tt * 16 + l15;
        const float bias = bs[o] + bn[o];
#pragma unroll
        for (int r = 0; r < 4; ++r)
            out[(m0 + quad * 4 + r) * C + o] = acc[r] + bias;
    }
}

extern "C" void kernel_launch(void* const* d_in, const int* in_sizes, int n_in,
                              void* d_out, int out_size, void* d_ws, size_t ws_size,
                              hipStream_t stream) {
    const float* x  = (const float*)d_in[0];
    const int*   ei = (const int*)d_in[1];
    const float* ew = (const float*)d_in[2];
    const float* Ws = (const float*)d_in[3];
    const float* bs = (const float*)d_in[4];
    const float* Wn = (const float*)d_in[5];
    const float* bn = (const float*)d_in[6];

    const int N = in_sizes[0] / C;   // 100000
    const int E = in_sizes[2];       // 1600000
    const int NBK = (N + BKT - 1) / BKT;   // 782

    char* p = (char*)d_ws;
    float* agg = (float*)p;                  p += (size_t)N * C * sizeof(float);  // 25.6MB
    unsigned short* xb = (unsigned short*)p;  p += (size_t)N * C * sizeof(short); // 12.8MB
    unsigned short* aggb = (unsigned short*)p; p += (size_t)N * C * sizeof(short);// 12.8MB
    int2* sorted = (int2*)p;                 p += (size_t)E * sizeof(int2);       // 12.8MB
    unsigned short* Wsb = (unsigned short*)p; p += (size_t)C * C * sizeof(short); // 8KB
    unsigned short* Wnb = (unsigned short*)p; p += (size_t)C * C * sizeof(short); // 8KB
    int* bhist = (int*)p;                    p += (size_t)MAXB * sizeof(int);
    int* boffs = (int*)p;                    p += (size_t)(MAXB + 1) * sizeof(int);
    int* bcur = (int*)p;                     p += (size_t)MAXB * sizeof(int);
    const size_t needed = (size_t)(p - (char*)d_ws);

    const int nTiles = N / 16;
    const int projBlocks = (nTiles + 3) / 4;

    if (needed <= ws_size && N <= (1 << 17) && NBK <= MAXB) {
        const int n4 = N * C / 4;
        hipMemsetAsync(bhist, 0, (size_t)NBK * sizeof(int), stream);
        prep_kernel<<<1024, 256, 0, stream>>>(ei, bhist, E, NBK, x, xb, n4,
                                              Ws, Wn, Wsb, Wnb);
        scan_kernel<<<1, 1024, 0, stream>>>(bhist, boffs, bcur, NBK);
        bin_kernel<<<(E + BINT - 1) / BINT, BTHR, 0, stream>>>(ei, ew, bcur, bhist,
                                                               sorted, E, NBK);
        agg_kernel<<<NBK, 512, 0, stream>>>(xb, sorted, boffs, agg, aggb, N);
        projb_kernel<<<projBlocks, 256, 0, stream>>>(xb, aggb, Wsb, bs, Wnb, bn,
                                                     (float*)d_out, N);
    } else {
        hipMemsetAsync(agg, 0, (size_t)N * C * sizeof(float), stream);
        scatter_kernel<<<2048, 256, 0, stream>>>(x, ei, ew, agg, E);
        proj_kernel<<<projBlocks, 256, 0, stream>>>(x, agg, Ws, bs, Wn, bn,
                                                    (float*)d_out, N);
    }
}